// Round 1
// baseline (328.743 us; speedup 1.0000x reference)
//
#include <hip/hip_runtime.h>
#include <hip/hip_bf16.h>
#include <math.h>

#define D_MODEL 1024
#define SEQ     1024
#define BATCH   4
#define NHEADS  16
#define HD      64

typedef __bf16 bf16x8 __attribute__((ext_vector_type(8)));
typedef __bf16 bf16x4 __attribute__((ext_vector_type(4)));
typedef float  f32x4  __attribute__((ext_vector_type(4)));

__device__ __forceinline__ f32x4 mfma16(bf16x8 a, bf16x8 b, f32x4 c) {
  return __builtin_amdgcn_mfma_f32_16x16x32_bf16(a, b, c, 0, 0, 0);
}

// ---------------------------------------------------------------- fp32->bf16
__global__ void cvt_kernel(const float* __restrict__ src, __bf16* __restrict__ dst, int n4) {
  int i = blockIdx.x * blockDim.x + threadIdx.x;
  if (i < n4) {
    float4 v = ((const float4*)src)[i];
    bf16x4 o;
    o[0] = (__bf16)v.x; o[1] = (__bf16)v.y; o[2] = (__bf16)v.z; o[3] = (__bf16)v.w;
    ((bf16x4*)dst)[i] = o;
  }
}

// ------------------------------------------------- k_imp / v_imp  [H,S] fp32
// one wave per output element; 32768 waves total
__global__ __launch_bounds__(256) void imp_kernel(
    const float* __restrict__ k_ema, const float* __restrict__ v_ema,
    const float* __restrict__ Wimp,  const float* __restrict__ bimp,
    float* __restrict__ kimp, float* __restrict__ vimp) {
  int gw   = blockIdx.x * 4 + (threadIdx.x >> 6);
  int lane = threadIdx.x & 63;
  int sel  = gw >> 14;
  int rem  = gw & 16383;
  int h = rem >> 10, s = rem & 1023;
  const float* ema = sel ? v_ema : k_ema;
  float sum = 0.f;
  for (int d = lane; d < D_MODEL; d += 64)
    sum += ema[s * D_MODEL + d] * Wimp[h * D_MODEL + d];
  for (int mm = 32; mm >= 1; mm >>= 1) sum += __shfl_xor(sum, mm);
  if (lane == 0) (sel ? vimp : kimp)[h * SEQ + s] = sum + bimp[h];
}

// ---------------------------------------------------- C[M,N] = A[M,K]·W[N,K]^T + bias
// 128x128 tile, BK=32, 4 waves in 2x2, each wave 64x64 via 4x4 MFMA subtiles
template<bool OUT_BF16>
__global__ __launch_bounds__(256) void gemm_bt(
    const __bf16* __restrict__ A,
    const __bf16* __restrict__ W0, const __bf16* __restrict__ W1, const __bf16* __restrict__ W2,
    const float* __restrict__ b0, const float* __restrict__ b1, const float* __restrict__ b2,
    void* out0, void* out1, void* out2) {
  const int z = blockIdx.z;
  const __bf16* W   = (z == 0) ? W0 : (z == 1) ? W1 : W2;
  const float* bias = (z == 0) ? b0 : (z == 1) ? b1 : b2;
  void* out         = (z == 0) ? out0 : (z == 1) ? out1 : out2;

  __shared__ __bf16 As[128][40];  // 32 + 8 pad: b128 reads land 2-way max
  __shared__ __bf16 Bs[128][40];

  const int tid = threadIdx.x;
  const int wave = tid >> 6, lane = tid & 63;
  const int quad = lane >> 4, l16 = lane & 15;
  const int wy = wave >> 1, wx = wave & 1;
  const int row0 = blockIdx.y * 128;
  const int col0 = blockIdx.x * 128;

  const f32x4 fzero = {0.f, 0.f, 0.f, 0.f};
  f32x4 acc[4][4];
  for (int i = 0; i < 4; i++)
    for (int j = 0; j < 4; j++) acc[i][j] = fzero;

  // staging: 512 chunks of 16B per tile; thread t does chunks t and t+256
  const int c0 = tid, c1 = tid + 256;
  const int r0 = c0 >> 2, k0c = (c0 & 3) * 8;
  const int r1 = c1 >> 2, k1c = (c1 & 3) * 8;

  for (int k0 = 0; k0 < D_MODEL; k0 += 32) {
    *(uint4*)&As[r0][k0c] = *(const uint4*)&A[(size_t)(row0 + r0) * D_MODEL + k0 + k0c];
    *(uint4*)&As[r1][k1c] = *(const uint4*)&A[(size_t)(row0 + r1) * D_MODEL + k0 + k1c];
    *(uint4*)&Bs[r0][k0c] = *(const uint4*)&W[(size_t)(col0 + r0) * D_MODEL + k0 + k0c];
    *(uint4*)&Bs[r1][k1c] = *(const uint4*)&W[(size_t)(col0 + r1) * D_MODEL + k0 + k1c];
    __syncthreads();
    bf16x8 af[4], bfr[4];
    for (int mi = 0; mi < 4; mi++) af[mi]  = *(const bf16x8*)&As[wy * 64 + mi * 16 + l16][quad * 8];
    for (int ni = 0; ni < 4; ni++) bfr[ni] = *(const bf16x8*)&Bs[wx * 64 + ni * 16 + l16][quad * 8];
    for (int mi = 0; mi < 4; mi++)
      for (int ni = 0; ni < 4; ni++)
        acc[mi][ni] = mfma16(af[mi], bfr[ni], acc[mi][ni]);
    __syncthreads();
  }

  for (int ni = 0; ni < 4; ni++) {
    const int col = col0 + wx * 64 + ni * 16 + l16;
    const float bv = bias[col];
    for (int mi = 0; mi < 4; mi++) {
      const int row = row0 + wy * 64 + mi * 16 + quad * 4;
      for (int r = 0; r < 4; r++) {
        float v = acc[mi][ni][r] + bv;
        if (OUT_BF16) ((__bf16*)out)[(size_t)(row + r) * D_MODEL + col] = (__bf16)v;
        else          ((float*)out)[(size_t)(row + r) * D_MODEL + col] = v;
      }
    }
  }
}

// ------------------------------------------------------- flash attention
// grid (S/64, B*H); block 256 = 4 waves, wave w owns q-rows [q0+16w, q0+16w+16)
__global__ __launch_bounds__(256) void attn_kernel(
    const __bf16* __restrict__ Qb, const __bf16* __restrict__ Kb, const __bf16* __restrict__ Vb,
    const float* __restrict__ kimp, const float* __restrict__ vimp,
    __bf16* __restrict__ Ob) {
  const int bh = blockIdx.y;
  const int b = bh >> 4, h = bh & 15;
  const int q0 = blockIdx.x * 64;
  const int tid = threadIdx.x;
  const int wave = tid >> 6, lane = tid & 63;
  const int quad = lane >> 4, l16 = lane & 15;

  __shared__ __bf16 Ks[32][72];      // K rows (d contiguous), pad 72 -> conflict-free-ish b128
  __shared__ __bf16 Vt[64][40];      // V transposed: Vt[d][key]
  __shared__ __bf16 Ps[4][16][40];   // per-wave P round-trip C-layout -> A-layout

  const int qrow_base = q0 + wave * 16;
  const __bf16* qptr = Qb + (size_t)(b * SEQ + qrow_base + l16) * D_MODEL + h * HD;
  bf16x8 qa0 = *(const bf16x8*)(qptr + quad * 8);
  bf16x8 qa1 = *(const bf16x8*)(qptr + 32 + quad * 8);

  float kimp_r[4];
  for (int r = 0; r < 4; r++)
    kimp_r[r] = 0.05f * kimp[h * SEQ + qrow_base + quad * 4 + r];

  const f32x4 fzero = {0.f, 0.f, 0.f, 0.f};
  float m_i[4], l_i[4];
  f32x4 o[4];
  for (int r = 0; r < 4; r++) { m_i[r] = -3.0e38f; l_i[r] = 0.f; }
  for (int t = 0; t < 4; t++) o[t] = fzero;

  const int key_stage = tid >> 3;       // 0..31
  const int d_stage   = (tid & 7) * 8;  // 0,8,..,56

  const int nch = (q0 >> 5) + 2;        // causal: keys < q0+64 only
  for (int ch = 0; ch < nch; ch++) {
    const int kc = ch * 32;
    {
      const size_t gidx = (size_t)(b * SEQ + kc + key_stage) * D_MODEL + h * HD + d_stage;
      *(uint4*)&Ks[key_stage][d_stage] = *(const uint4*)(Kb + gidx);
      bf16x8 vv = *(const bf16x8*)(Vb + gidx);
      for (int j = 0; j < 8; j++) Vt[d_stage + j][key_stage] = vv[j];
    }
    __syncthreads();

    // S = Q·K^T for 16 rows x 32 keys
    f32x4 s0 = fzero, s1 = fzero;
    {
      bf16x8 kb0 = *(const bf16x8*)&Ks[l16][quad * 8];
      bf16x8 kb1 = *(const bf16x8*)&Ks[l16][32 + quad * 8];
      s0 = mfma16(qa0, kb0, s0);
      s0 = mfma16(qa1, kb1, s0);
      bf16x8 kb2 = *(const bf16x8*)&Ks[16 + l16][quad * 8];
      bf16x8 kb3 = *(const bf16x8*)&Ks[16 + l16][32 + quad * 8];
      s1 = mfma16(qa0, kb2, s1);
      s1 = mfma16(qa1, kb3, s1);
    }

    const float vi0 = 0.05f * vimp[h * SEQ + kc + l16];
    const float vi1 = 0.05f * vimp[h * SEQ + kc + 16 + l16];

    float alpha[4], p0[4], p1[4];
    for (int r = 0; r < 4; r++) {
      const int qrow = qrow_base + quad * 4 + r;
      float x0 = s0[r] * 0.125f + kimp_r[r] + vi0;
      float x1 = s1[r] * 0.125f + kimp_r[r] + vi1;
      if (kc + l16 > qrow)      x0 = -3.0e38f;   // causal mask (finite: avoids inf-inf NaN)
      if (kc + 16 + l16 > qrow) x1 = -3.0e38f;
      float mx = fmaxf(x0, x1);
      for (int mm = 8; mm >= 1; mm >>= 1) mx = fmaxf(mx, __shfl_xor(mx, mm));
      const float mnew = fmaxf(m_i[r], mx);
      alpha[r] = __expf(m_i[r] - mnew);
      p0[r] = __expf(x0 - mnew);
      p1[r] = __expf(x1 - mnew);
      float rs = p0[r] + p1[r];
      for (int mm = 8; mm >= 1; mm >>= 1) rs += __shfl_xor(rs, mm);
      l_i[r] = l_i[r] * alpha[r] + rs;
      m_i[r] = mnew;
    }

    for (int t = 0; t < 4; t++)
      for (int r = 0; r < 4; r++) o[t][r] *= alpha[r];

    // P: C-layout -> LDS -> A-layout (per-wave buffer; barrier below covers visibility)
    for (int r = 0; r < 4; r++) {
      Ps[wave][quad * 4 + r][l16]      = (__bf16)p0[r];
      Ps[wave][quad * 4 + r][16 + l16] = (__bf16)p1[r];
    }
    __syncthreads();

    bf16x8 pa = *(const bf16x8*)&Ps[wave][l16][quad * 8];
    for (int t = 0; t < 4; t++) {
      bf16x8 vb = *(const bf16x8*)&Vt[t * 16 + l16][quad * 8];
      o[t] = mfma16(pa, vb, o[t]);
    }
    __syncthreads();  // protect Ks/Vt before next chunk's staging
  }

  for (int t = 0; t < 4; t++) {
    for (int r = 0; r < 4; r++) {
      const int qrow = qrow_base + quad * 4 + r;
      float val = o[t][r] / l_i[r];
      Ob[(size_t)(b * SEQ + qrow) * D_MODEL + h * HD + t * 16 + l16] = (__bf16)val;
    }
  }
}

// ---------------------------------------------------------------------------
extern "C" void kernel_launch(void* const* d_in, const int* in_sizes, int n_in,
                              void* d_out, int out_size, void* d_ws, size_t ws_size,
                              hipStream_t stream) {
  const float* x     = (const float*)d_in[0];
  const float* Wq    = (const float*)d_in[1];
  const float* bq    = (const float*)d_in[2];
  const float* Wk    = (const float*)d_in[3];
  const float* bk    = (const float*)d_in[4];
  const float* Wv    = (const float*)d_in[5];
  const float* bv    = (const float*)d_in[6];
  const float* Wo    = (const float*)d_in[7];
  const float* bo    = (const float*)d_in[8];
  const float* Wimp  = (const float*)d_in[9];
  const float* bimp  = (const float*)d_in[10];
  const float* k_ema = (const float*)d_in[11];
  const float* v_ema = (const float*)d_in[12];
  float* out = (float*)d_out;

  char* ws = (char*)d_ws;
  __bf16* x_bf  = (__bf16*)(ws);                        // 8 MB
  __bf16* wq_bf = (__bf16*)(ws + (8ull  << 20));        // 2 MB
  __bf16* wk_bf = (__bf16*)(ws + (10ull << 20));
  __bf16* wv_bf = (__bf16*)(ws + (12ull << 20));
  __bf16* wo_bf = (__bf16*)(ws + (14ull << 20));
  __bf16* q_bf  = (__bf16*)(ws + (16ull << 20));        // 8 MB each
  __bf16* k_bf  = (__bf16*)(ws + (24ull << 20));
  __bf16* v_bf  = (__bf16*)(ws + (32ull << 20));
  __bf16* a_bf  = (__bf16*)(ws + (40ull << 20));
  float*  kimp  = (float*)(ws + (48ull << 20));         // 64 KB
  float*  vimp  = (float*)(ws + (48ull << 20) + (64ull << 10));

  // fp32 -> bf16
  cvt_kernel<<<4096, 256, 0, stream>>>(x,  x_bf,  (BATCH * SEQ * D_MODEL) / 4);
  cvt_kernel<<<1024, 256, 0, stream>>>(Wq, wq_bf, (D_MODEL * D_MODEL) / 4);
  cvt_kernel<<<1024, 256, 0, stream>>>(Wk, wk_bf, (D_MODEL * D_MODEL) / 4);
  cvt_kernel<<<1024, 256, 0, stream>>>(Wv, wv_bf, (D_MODEL * D_MODEL) / 4);
  cvt_kernel<<<1024, 256, 0, stream>>>(Wo, wo_bf, (D_MODEL * D_MODEL) / 4);

  // importance vectors
  imp_kernel<<<8192, 256, 0, stream>>>(k_ema, v_ema, Wimp, bimp, kimp, vimp);

  // Q,K,V projections (fused over grid.z)
  gemm_bt<true><<<dim3(8, 32, 3), 256, 0, stream>>>(
      x_bf, wq_bf, wk_bf, wv_bf, bq, bk, bv, (void*)q_bf, (void*)k_bf, (void*)v_bf);

  // fused causal attention with importance bias
  attn_kernel<<<dim3(SEQ / 64, BATCH * NHEADS), 256, 0, stream>>>(
      q_bf, k_bf, v_bf, kimp, vimp, a_bf);

  // output projection, fp32 out
  gemm_bt<false><<<dim3(8, 32, 1), 256, 0, stream>>>(
      a_bf, wo_bf, wo_bf, wo_bf, bo, bo, bo, (void*)out, (void*)out, (void*)out);
}

// Round 3
// 244.950 us; speedup vs baseline: 1.3421x; 1.3421x over previous
//
#include <hip/hip_runtime.h>
#include <hip/hip_bf16.h>
#include <math.h>

#define D_MODEL 1024
#define SEQ     1024
#define BATCH   4
#define NHEADS  16
#define HD      64

// log2(e) folds: p = exp2(s') with s' = (q.k)*0.125*log2e + 0.05*log2e*(kimp+vimp)
#define QSC 0.18033688f   // 0.125 * log2(e)
#define BSC 0.072134752f  // 0.05  * log2(e)

typedef __bf16 bf16x8 __attribute__((ext_vector_type(8)));
typedef __bf16 bf16x4 __attribute__((ext_vector_type(4)));
typedef float  f32x4  __attribute__((ext_vector_type(4)));

__device__ __forceinline__ f32x4 mfma16(bf16x8 a, bf16x8 b, f32x4 c) {
  return __builtin_amdgcn_mfma_f32_16x16x32_bf16(a, b, c, 0, 0, 0);
}

// async global->LDS, 16B per lane; LDS dest = wave-uniform base + lane*16
__device__ __forceinline__ void async16(__bf16* lds, const __bf16* g) {
  __builtin_amdgcn_global_load_lds(g, lds, 16, 0, 0);
}

// ---------------------------------------------------------------- fp32->bf16
__global__ void cvt_kernel(const float* __restrict__ src, __bf16* __restrict__ dst, int n4) {
  int i = blockIdx.x * blockDim.x + threadIdx.x;
  if (i < n4) {
    float4 v = ((const float4*)src)[i];
    bf16x4 o;
    o[0] = (__bf16)v.x; o[1] = (__bf16)v.y; o[2] = (__bf16)v.z; o[3] = (__bf16)v.w;
    ((bf16x4*)dst)[i] = o;
  }
}

// all four weight matrices in one launch (1M elems each)
__global__ void cvtw_kernel(const float* __restrict__ s0, const float* __restrict__ s1,
                            const float* __restrict__ s2, const float* __restrict__ s3,
                            __bf16* __restrict__ d0, __bf16* __restrict__ d1,
                            __bf16* __restrict__ d2, __bf16* __restrict__ d3) {
  int i = blockIdx.x * blockDim.x + threadIdx.x;   // 0 .. 4*262144-1
  int sel = i >> 18;
  int j = i & 262143;
  const float* s = (sel == 0) ? s0 : (sel == 1) ? s1 : (sel == 2) ? s2 : s3;
  __bf16* d      = (sel == 0) ? d0 : (sel == 1) ? d1 : (sel == 2) ? d2 : d3;
  float4 v = ((const float4*)s)[j];
  bf16x4 o;
  o[0] = (__bf16)v.x; o[1] = (__bf16)v.y; o[2] = (__bf16)v.z; o[3] = (__bf16)v.w;
  ((bf16x4*)d)[j] = o;
}

// ------------------------------------------------- k_imp / v_imp  [H,S] fp32
__global__ __launch_bounds__(256) void imp_kernel(
    const float* __restrict__ k_ema, const float* __restrict__ v_ema,
    const float* __restrict__ Wimp,  const float* __restrict__ bimp,
    float* __restrict__ kimp, float* __restrict__ vimp) {
  int gw   = blockIdx.x * 4 + (threadIdx.x >> 6);
  int lane = threadIdx.x & 63;
  int sel  = gw >> 14;
  int rem  = gw & 16383;
  int h = rem >> 10, s = rem & 1023;
  const float* ema = sel ? v_ema : k_ema;
  float sum = 0.f;
  for (int d = lane; d < D_MODEL; d += 64)
    sum += ema[s * D_MODEL + d] * Wimp[h * D_MODEL + d];
  for (int mm = 32; mm >= 1; mm >>= 1) sum += __shfl_xor(sum, mm);
  if (lane == 0) (sel ? vimp : kimp)[h * SEQ + s] = sum + bimp[h];
}

// ---------------------------------------------------- C[M,N] = (A[M,K]·W[N,K]^T + bias)*sc
// m97 structure: 128x128 tile, BK=32, global_load_lds width-16 into swizzled [128][32]
template<bool OUT_BF16>
__global__ __launch_bounds__(256) void gemm_bt(
    const __bf16* __restrict__ A,
    const __bf16* __restrict__ W0, const __bf16* __restrict__ W1, const __bf16* __restrict__ W2,
    const float* __restrict__ b0, const float* __restrict__ b1, const float* __restrict__ b2,
    void* out0, void* out1, void* out2, float sc0, float sc1, float sc2) {
  const int z = blockIdx.z;
  const __bf16* W   = (z == 0) ? W0 : (z == 1) ? W1 : W2;
  const float* bias = (z == 0) ? b0 : (z == 1) ? b1 : b2;
  void* out         = (z == 0) ? out0 : (z == 1) ? out1 : out2;
  const float sc    = (z == 0) ? sc0 : (z == 1) ? sc1 : sc2;

  // flat [128][32] bf16, k-groups of 8 xor-swizzled by (row&3): content at
  // [row][g*8+j] = global[row][k0 + ((g^(row&3))*8)+j]
  __shared__ __bf16 As[128 * 32];
  __shared__ __bf16 Bs[128 * 32];

  const int tid = threadIdx.x;
  const int w = tid >> 6, l = tid & 63;
  const int quad = l >> 4, l16 = l & 15;
  const int wy = w >> 1, wx = w & 1;
  const int row0 = blockIdx.y * 128;
  const int col0 = blockIdx.x * 128;

  const f32x4 fzero = {0.f, 0.f, 0.f, 0.f};
  f32x4 acc[4][4];
  for (int i = 0; i < 4; i++)
    for (int j = 0; j < 4; j++) acc[i][j] = fzero;

  // staging: instr i covers flat elems i*2048 + (w*64+l)*8 (rows i*64 + w*16 + l/4)
  const int lr = l >> 2;                         // 0..15
  const int sw0 = (((l & 3) ^ (lr & 3)) * 8);    // source k offset (swizzled)
  const int rowA = w * 16 + lr;                  // instr0 row; instr1 = +64 (same &3)
  const __bf16* aptr = A + (size_t)(row0 + rowA) * D_MODEL + sw0;
  const __bf16* bptr = W + (size_t)(col0 + rowA) * D_MODEL + sw0;
  __bf16* lA0 = &As[w * 512 + l * 8];
  __bf16* lA1 = &As[2048 + w * 512 + l * 8];     // FIX: rows 64..127 start at flat 2048
  __bf16* lB0 = &Bs[w * 512 + l * 8];
  __bf16* lB1 = &Bs[2048 + w * 512 + l * 8];

  const int rswz = (quad ^ (l16 & 3)) * 8;       // frag-read swizzled offset

  for (int k0 = 0; k0 < D_MODEL; k0 += 32) {
    async16(lA0, aptr + k0);
    async16(lA1, aptr + (size_t)64 * D_MODEL + k0);
    async16(lB0, bptr + k0);
    async16(lB1, bptr + (size_t)64 * D_MODEL + k0);
    __syncthreads();
    bf16x8 af[4], bfr[4];
    #pragma unroll
    for (int mi = 0; mi < 4; mi++) af[mi]  = *(const bf16x8*)&As[(wy * 64 + mi * 16 + l16) * 32 + rswz];
    #pragma unroll
    for (int ni = 0; ni < 4; ni++) bfr[ni] = *(const bf16x8*)&Bs[(wx * 64 + ni * 16 + l16) * 32 + rswz];
    #pragma unroll
    for (int mi = 0; mi < 4; mi++)
      #pragma unroll
      for (int ni = 0; ni < 4; ni++)
        acc[mi][ni] = mfma16(af[mi], bfr[ni], acc[mi][ni]);
    __syncthreads();
  }

  #pragma unroll
  for (int ni = 0; ni < 4; ni++) {
    const int col = col0 + wx * 64 + ni * 16 + l16;
    const float bv = bias[col];
    #pragma unroll
    for (int mi = 0; mi < 4; mi++) {
      const int row = row0 + wy * 64 + mi * 16 + quad * 4;
      #pragma unroll
      for (int r = 0; r < 4; r++) {
        float v = (acc[mi][ni][r] + bv) * sc;
        if (OUT_BF16) ((__bf16*)out)[(size_t)(row + r) * D_MODEL + col] = (__bf16)v;
        else          ((float*)out)[(size_t)(row + r) * D_MODEL + col] = v;
      }
    }
  }
}

// ------------------------------------------------------- flash attention (transposed)
// S^T = K·Q^T and O^T = V^T·P so q-row == lane&15: softmax state is per-lane scalar.
// 64-key chunks; K frags direct from global; V transposed into swizzled+padded LDS.
__global__ __launch_bounds__(256) void attn_kernel(
    const __bf16* __restrict__ Qb, const __bf16* __restrict__ Kb, const __bf16* __restrict__ Vb,
    const float* __restrict__ kimp, const float* __restrict__ vimp,
    __bf16* __restrict__ Ob) {
  const int id = blockIdx.x;
  const int qt = id >> 6;          // 0..15 (balanced across CUs: CU gets qt, qt+4, qt+8, qt+12)
  const int bh = id & 63;
  const int b = bh >> 4, h = bh & 15;
  const int q0 = qt * 64;
  const int tid = threadIdx.x;
  const int wave = tid >> 6, lane = tid & 63;
  const int quad = lane >> 4, l16 = lane & 15;

  // Vt[buf][d][key'] with key' = key ^ (((d>>3)&3)*8); stride 72 breaks read conflicts
  __shared__ __bf16 Vt[2][64][72];
  __shared__ __bf16 Ps[4][16][72];   // per-wave P round-trip [q=l16][key]

  const int qrow = q0 + wave * 16 + l16;
  const __bf16* qptr = Qb + (size_t)(b * SEQ + qrow) * D_MODEL + h * HD;
  bf16x8 qa0 = *(const bf16x8*)(qptr + quad * 8);        // Q pre-scaled by QSC in gemm
  bf16x8 qa1 = *(const bf16x8*)(qptr + 32 + quad * 8);
  const float ks_s = BSC * kimp[h * SEQ + qrow];

  float m_i = -3.0e38f, l_i = 0.f;
  f32x4 o[4];
  #pragma unroll
  for (int t = 0; t < 4; t++) { o[t][0] = 0.f; o[t][1] = 0.f; o[t][2] = 0.f; o[t][3] = 0.f; }

  // V staging: thread -> key pair (2pr, 2pr+1), d-group dg*8..+7; good coalescing,
  // write banks 4-way (swizzle), read banks 2-way (pad)
  const int pr = (tid >> 3) & 31;
  const int dg = tid & 7;
  const int vswz = (dg & 3) * 8;
  const int kpos = (2 * pr) ^ vswz;
  const __bf16* vbase = Vb + (size_t)(b * SEQ) * D_MODEL + h * HD;
  const __bf16* kbase = Kb + (size_t)(b * SEQ) * D_MODEL + h * HD;

  const int nch = qt + 1;
  for (int ch = 0; ch < nch; ch++) {
    const int kc = ch * 64;
    const int buf = ch & 1;
    // --- stage V chunk (global loads first for latency)
    const __bf16* v0 = vbase + (size_t)(kc + 2 * pr) * D_MODEL + dg * 8;
    bf16x8 va = *(const bf16x8*)v0;
    bf16x8 vb = *(const bf16x8*)(v0 + D_MODEL);
    // --- K fragments direct from global (L1-hot across waves)
    bf16x8 kf[4][2];
    #pragma unroll
    for (int t = 0; t < 4; t++) {
      const __bf16* kp = kbase + (size_t)(kc + t * 16 + l16) * D_MODEL;
      kf[t][0] = *(const bf16x8*)(kp + quad * 8);
      kf[t][1] = *(const bf16x8*)(kp + 32 + quad * 8);
    }
    #pragma unroll
    for (int j = 0; j < 8; j++) {
      union { __bf16 hh[2]; int ii; } u;
      u.hh[0] = va[j]; u.hh[1] = vb[j];
      *(int*)&Vt[buf][dg * 8 + j][kpos] = u.ii;
    }
    __syncthreads();

    // --- S^T tiles [key][q]; bias pre-loaded into accumulator
    const bool diag = (ch == nch - 1);
    float x[4][4];
    float mc = -3.0e38f;
    #pragma unroll
    for (int t = 0; t < 4; t++) {
      const float4 vi = *(const float4*)&vimp[h * SEQ + kc + t * 16 + quad * 4];
      f32x4 acc;
      acc[0] = ks_s + BSC * vi.x; acc[1] = ks_s + BSC * vi.y;
      acc[2] = ks_s + BSC * vi.z; acc[3] = ks_s + BSC * vi.w;
      acc = mfma16(kf[t][0], qa0, acc);
      acc = mfma16(kf[t][1], qa1, acc);
      #pragma unroll
      for (int r = 0; r < 4; r++) {
        float xx = acc[r];
        if (diag && (kc + t * 16 + quad * 4 + r > qrow)) xx = -3.0e38f;
        x[t][r] = xx;
        mc = fmaxf(mc, xx);
      }
    }
    mc = fmaxf(mc, __shfl_xor(mc, 16));
    mc = fmaxf(mc, __shfl_xor(mc, 32));
    const float mnew = fmaxf(m_i, mc);
    const float alpha = exp2f(m_i - mnew);
    m_i = mnew;
    float p[4][4];
    float rs = 0.f;
    #pragma unroll
    for (int t = 0; t < 4; t++)
      #pragma unroll
      for (int r = 0; r < 4; r++) { p[t][r] = exp2f(x[t][r] - mnew); rs += p[t][r]; }
    rs += __shfl_xor(rs, 16);
    rs += __shfl_xor(rs, 32);
    l_i = l_i * alpha + rs;
    #pragma unroll
    for (int t = 0; t < 4; t++) {
      o[t][0] *= alpha; o[t][1] *= alpha; o[t][2] *= alpha; o[t][3] *= alpha;
    }

    // --- P: C-layout [key][q] -> per-wave LDS -> B-frag [q][key]
    #pragma unroll
    for (int t = 0; t < 4; t++) {
      union { __bf16 hh[2]; int ii; } u0, u1;
      u0.hh[0] = (__bf16)p[t][0]; u0.hh[1] = (__bf16)p[t][1];
      u1.hh[0] = (__bf16)p[t][2]; u1.hh[1] = (__bf16)p[t][3];
      *(int*)&Ps[wave][l16][t * 16 + quad * 4]     = u0.ii;
      *(int*)&Ps[wave][l16][t * 16 + quad * 4 + 2] = u1.ii;
    }
    bf16x8 pf0 = *(const bf16x8*)&Ps[wave][l16][quad * 8];
    bf16x8 pf1 = *(const bf16x8*)&Ps[wave][l16][32 + quad * 8];

    // --- O^T += V^T · P
    #pragma unroll
    for (int td = 0; td < 4; td++) {
      const int d0 = td * 16 + l16;
      const int g = ((d0 >> 3) & 3) * 8;
      bf16x8 vf0 = *(const bf16x8*)&Vt[buf][d0][(quad * 8) ^ g];
      bf16x8 vf1 = *(const bf16x8*)&Vt[buf][d0][32 + ((quad * 8) ^ g)];
      o[td] = mfma16(vf0, pf0, o[td]);
      o[td] = mfma16(vf1, pf1, o[td]);
    }
  }

  const float inv_l = 1.0f / l_i;
  __bf16* op = Ob + (size_t)(b * SEQ + qrow) * D_MODEL + h * HD;
  #pragma unroll
  for (int td = 0; td < 4; td++) {
    union { __bf16 hh[2]; int ii; } u0, u1;
    u0.hh[0] = (__bf16)(o[td][0] * inv_l); u0.hh[1] = (__bf16)(o[td][1] * inv_l);
    u1.hh[0] = (__bf16)(o[td][2] * inv_l); u1.hh[1] = (__bf16)(o[td][3] * inv_l);
    *(int*)(op + td * 16 + quad * 4)     = u0.ii;
    *(int*)(op + td * 16 + quad * 4 + 2) = u1.ii;
  }
}

// ---------------------------------------------------------------------------
extern "C" void kernel_launch(void* const* d_in, const int* in_sizes, int n_in,
                              void* d_out, int out_size, void* d_ws, size_t ws_size,
                              hipStream_t stream) {
  const float* x     = (const float*)d_in[0];
  const float* Wq    = (const float*)d_in[1];
  const float* bq    = (const float*)d_in[2];
  const float* Wk    = (const float*)d_in[3];
  const float* bk    = (const float*)d_in[4];
  const float* Wv    = (const float*)d_in[5];
  const float* bv    = (const float*)d_in[6];
  const float* Wo    = (const float*)d_in[7];
  const float* bo    = (const float*)d_in[8];
  const float* Wimp  = (const float*)d_in[9];
  const float* bimp  = (const float*)d_in[10];
  const float* k_ema = (const float*)d_in[11];
  const float* v_ema = (const float*)d_in[12];
  float* out = (float*)d_out;

  char* ws = (char*)d_ws;
  __bf16* x_bf  = (__bf16*)(ws);                        // 8 MB
  __bf16* wq_bf = (__bf16*)(ws + (8ull  << 20));        // 2 MB each
  __bf16* wk_bf = (__bf16*)(ws + (10ull << 20));
  __bf16* wv_bf = (__bf16*)(ws + (12ull << 20));
  __bf16* wo_bf = (__bf16*)(ws + (14ull << 20));
  __bf16* q_bf  = (__bf16*)(ws + (16ull << 20));        // 8 MB each
  __bf16* k_bf  = (__bf16*)(ws + (24ull << 20));
  __bf16* v_bf  = (__bf16*)(ws + (32ull << 20));
  __bf16* a_bf  = (__bf16*)(ws + (40ull << 20));
  float*  kimp  = (float*)(ws + (48ull << 20));         // 64 KB
  float*  vimp  = (float*)(ws + (48ull << 20) + (64ull << 10));

  cvt_kernel<<<4096, 256, 0, stream>>>(x, x_bf, (BATCH * SEQ * D_MODEL) / 4);
  cvtw_kernel<<<4096, 256, 0, stream>>>(Wq, Wk, Wv, Wo, wq_bf, wk_bf, wv_bf, wo_bf);
  imp_kernel<<<8192, 256, 0, stream>>>(k_ema, v_ema, Wimp, bimp, kimp, vimp);

  // Q,K,V projections; Q pre-scaled by 0.125*log2(e) for exp2-domain softmax
  gemm_bt<true><<<dim3(8, 32, 3), 256, 0, stream>>>(
      x_bf, wq_bf, wk_bf, wv_bf, bq, bk, bv,
      (void*)q_bf, (void*)k_bf, (void*)v_bf, QSC, 1.0f, 1.0f);

  attn_kernel<<<dim3(SEQ / 64 * BATCH * NHEADS), 256, 0, stream>>>(
      q_bf, k_bf, v_bf, kimp, vimp, a_bf);

  gemm_bt<false><<<dim3(8, 32, 1), 256, 0, stream>>>(
      a_bf, wo_bf, wo_bf, wo_bf, bo, bo, bo,
      (void*)out, (void*)out, (void*)out, 1.0f, 1.0f, 1.0f);
}